// Round 10
// baseline (173.373 us; speedup 1.0000x reference)
//
#include <hip/hip_runtime.h>

#define EPS 1e-5f

typedef float f32x4 __attribute__((ext_vector_type(4)));
typedef short bf16x8 __attribute__((ext_vector_type(8)));

__device__ __forceinline__ unsigned short f2bf(float f) {
  unsigned int u = __builtin_bit_cast(unsigned int, f);
  u = (u + 0x7FFFu + ((u >> 16) & 1u)) >> 16;
  return (unsigned short)u;
}

// HW packed f32->bf16 (RNE, identical rounding to f2bf): D[15:0]=cvt(a),
// D[31:16]=cvt(b).  One VALU op replacing ~9.
__device__ __forceinline__ unsigned int cvt2(float a, float b) {
  unsigned int r;
  asm("v_cvt_pk_bf16_f32 %0, %1, %2" : "=v"(r) : "v"(a), "v"(b));
  return r;
}

// ---------------------------------------------------------------------------
// Prep (verified, unchanged from r7): fold BN into weights; MFMA A-fragment
// layout (bf16), REFERENCE k-order.  idx = ((ks*CT + ct)*64 + lane)*8 + j
//   <-> A[ch = ct*16 + (lane&15)][k = ks*32 + (lane>>4)*8 + j]
// ---------------------------------------------------------------------------
__global__ __launch_bounds__(256) void k_prep(
    const float* __restrict__ w1, const float* __restrict__ b1,
    const float* __restrict__ g1, const float* __restrict__ be1,
    const float* __restrict__ m1, const float* __restrict__ v1,
    const float* __restrict__ w2, const float* __restrict__ b2,
    const float* __restrict__ g2, const float* __restrict__ be2,
    const float* __restrict__ m2, const float* __restrict__ v2,
    float* __restrict__ beta1, float* __restrict__ beta2,
    unsigned short* __restrict__ w1b, unsigned short* __restrict__ w2f)
{
  int t = blockIdx.x * 256 + threadIdx.x;
  if (t < 139264) {   // w2 fragments: 17 ks * 16 ct * 64 lanes * 8
    int j = t & 7, l = (t >> 3) & 63, g = t >> 9;
    int ct = g & 15, ks = g >> 4;
    int k = ks * 32 + (l >> 4) * 8 + j;
    int ch = ct * 16 + (l & 15);
    float val = 0.f;
    if (k < 528) {
      float s2 = g2[ch] * rsqrtf(v2[ch] + EPS);
      val = w2[ch * 528 + k] * s2;
    }
    w2f[t] = f2bf(val);
  }
  if (t < 8192) {     // w1 fragments: 8 ks * 2 ct * 64 lanes * 8
    int j = t & 7, l = (t >> 3) & 63, g = t >> 9;
    int ct = g & 1, ks = g >> 1;
    int c = ks * 32 + (l >> 4) * 8 + j;
    int m = ct * 16 + (l & 15);
    float s1 = g1[m] * rsqrtf(v1[m] + EPS);
    w1b[t] = f2bf(w1[m * 256 + c] * s1);
  }
  if (t < 32) {
    float s1 = g1[t] * rsqrtf(v1[t] + EPS);
    beta1[t] = (b1[t] - m1[t]) * s1 + be1[t];
  }
  if (t < 256) {
    float s2 = g2[t] * rsqrtf(v2[t] + EPS);
    beta2[t] = (b2[t] - m2[t]) * s2 + be2[t];
  }
}

// Write diag I (reference order, len 32-I at base(I)) from register y-row.
template<int I>
__device__ __forceinline__ void do_diag(const float* __restrict__ y,
                                        unsigned short* __restrict__ pr)
{
  constexpr int L = 32 - I;
  constexpr int base = 32 * I - (I * (I - 1)) / 2;
  float p[L];
#pragma unroll
  for (int j = 0; j < L; ++j) p[j] = y[I + j] * y[j];
  constexpr int s = (base & 1) ? 1 : 0;
  if constexpr (s != 0) pr[base] = f2bf(p[0]);
#pragma unroll
  for (int j = s; j + 1 < L; j += 2)
    *(unsigned int*)&pr[base + j] = cvt2(p[j], p[j + 1]);
  if constexpr (((L - s) & 1) != 0) pr[base + L - 1] = f2bf(p[L - 1]);
}

// Balanced set: diags {S, 31-S, S+8, 23-S} = 66 products for every S.
template<int S>
__device__ __forceinline__ void do_set(const float* __restrict__ y,
                                       unsigned short* __restrict__ pr)
{
  do_diag<S>(y, pr);
  do_diag<31 - S>(y, pr);
  do_diag<S + 8>(y, pr);
  do_diag<23 - S>(y, pr);
}

// ---------------------------------------------------------------------------
// Fused, 32-pixel tiles.  Grid 1024, each block runs tiles g and g+1024
// with cross-tile x-prefetch: tile t+1's x-loads issue right after tile
// t's xt-ready barrier and land one full tile later (latency hidden under
// P1+P2+P3).  Per tile:
//  P0w: xr regs -> bf16 [px][276] tile (xt aliases pk)       (barrier)
//       [t==0: issue tile-1 x loads]
//  P1: layer1 MFMA -> yf f32 [px][34]                        (barrier)
//  P2: y-row -> regs; static diag products -> pk              (barrier)
//  P3: layer2 MFMA 17 ks x 4 ct x 2 pt per wave + BN/relu + stores
// LDS: pk 35072B + yf 4352B = 39424B -> 4 blocks/CU.
// ---------------------------------------------------------------------------
__global__ __launch_bounds__(256, 4) void k_fused(
    const float* __restrict__ x, const unsigned short* __restrict__ w1b,
    const float* __restrict__ beta1, const unsigned short* __restrict__ w2f,
    const float* __restrict__ beta2, float* __restrict__ out)
{
  __shared__ __align__(16) unsigned short pk[32 * 548];
  __shared__ __align__(8) float yf[32 * 34];
  int tid = threadIdx.x;
  int wv = tid >> 6, lane = tid & 63;
  int l15 = lane & 15, l4 = lane >> 4;
  int g = blockIdx.x;
  int q = tid & 7;          // px quad (4*q .. 4*q+3)
  int cg = tid >> 3;        // channel-quad index within pass (0..31)

  // prologue: issue tile-0 x loads into registers
  float4 xr[8];
  {
    int pb = g * 32;
    const float* xb = x + ((size_t)(pb >> 12) << 20) + (pb & 4095);
#pragma unroll
    for (int pass = 0; pass < 2; ++pass)
#pragma unroll
      for (int i = 0; i < 4; ++i)
        xr[pass * 4 + i] =
            *(const float4*)&xb[(size_t)(4 * (cg + pass * 32) + i) * 4096 + 4 * q];
  }

  for (int t = 0; t < 2; ++t) {
    int tile = g + t * 1024;
    int pb = tile * 32;
    int b = pb >> 12, hw0 = pb & 4095;

    if (t) __syncthreads();   // prev P3 done reading pk before xt overwrite

    // ---- P0w: write prefetched regs -> bf16 transposed tile
    unsigned short* xt = pk;
#pragma unroll
    for (int pass = 0; pass < 2; ++pass) {
      int c4 = cg + pass * 32;
#pragma unroll
      for (int s = 0; s < 4; ++s) {
        const float* v0 = (const float*)&xr[pass * 4 + 0];
        const float* v1 = (const float*)&xr[pass * 4 + 1];
        const float* v2 = (const float*)&xr[pass * 4 + 2];
        const float* v3 = (const float*)&xr[pass * 4 + 3];
        *(uint2*)&xt[(4 * q + s) * 276 + 4 * c4] =
            make_uint2(cvt2(v0[s], v1[s]), cvt2(v2[s], v3[s]));
      }
    }
    __syncthreads();          // xt ready

    // issue tile-1 x loads; latency hides under P1+P2+P3 of tile 0
    if (t == 0) {
      int pb1 = (g + 1024) * 32;
      const float* xb1 = x + ((size_t)(pb1 >> 12) << 20) + (pb1 & 4095);
#pragma unroll
      for (int pass = 0; pass < 2; ++pass)
#pragma unroll
        for (int i = 0; i < 4; ++i)
          xr[pass * 4 + i] =
              *(const float4*)&xb1[(size_t)(4 * (cg + pass * 32) + i) * 4096 + 4 * q];
    }

    // ---- P1: layer1 MFMA; wave = (pxt = wv&1, mt = wv>>1) 16x16 tile
    {
      int pxt = wv & 1, mt = wv >> 1;
      int px = pxt * 16 + l15;
      f32x4 acc1 = (f32x4){0.f, 0.f, 0.f, 0.f};
      const uint4* w1b4 = (const uint4*)w1b;
#pragma unroll
      for (int ks = 0; ks < 8; ++ks) {
        union { uint4 q; bf16x8 v; } A, B;
        A.q = w1b4[(ks * 2 + mt) * 64 + lane];
        const unsigned short* s = &xt[px * 276 + ks * 32 + l4 * 8];
        uint2 lo = *(const uint2*)s;
        uint2 hi = *(const uint2*)(s + 4);
        B.q = make_uint4(lo.x, lo.y, hi.x, hi.y);
        acc1 = __builtin_amdgcn_mfma_f32_16x16x32_bf16(A.v, B.v, acc1, 0, 0, 0);
      }
      int m0 = mt * 16 + l4 * 4;
#pragma unroll
      for (int r = 0; r < 4; ++r)
        yf[px * 34 + m0 + r] = fmaxf(acc1[r] + beta1[m0 + r], 0.f);
    }
    __syncthreads();   // xt consumed AND yf ready; pk region free

    // ---- P2: register-sourced bilinear products, reference diag order
    {
      int px2 = tid & 31, set = tid >> 5;
      const float* yr = &yf[px2 * 34];
      unsigned short* pr = &pk[px2 * 548];
      float y[32];
#pragma unroll
      for (int k = 0; k < 16; ++k) {
        float2 v = *(const float2*)&yr[2 * k];
        y[2 * k] = v.x; y[2 * k + 1] = v.y;
      }
      switch (set) {
        case 0: do_set<0>(y, pr); break;
        case 1: do_set<1>(y, pr); break;
        case 2: do_set<2>(y, pr); break;
        case 3: do_set<3>(y, pr); break;
        case 4: do_set<4>(y, pr); break;
        case 5: do_set<5>(y, pr); break;
        case 6: do_set<6>(y, pr); break;
        default: do_set<7>(y, pr); break;
      }
      if (set < 4) {   // zero K-pad slots 528..543
        *(unsigned int*)&pr[528 + set * 4] = 0u;
        *(unsigned int*)&pr[530 + set * 4] = 0u;
      }
    }

    float bet[4][4];
#pragma unroll
    for (int ctl = 0; ctl < 4; ++ctl)
#pragma unroll
      for (int r = 0; r < 4; ++r)
        bet[ctl][r] = beta2[(wv * 4 + ctl) * 16 + l4 * 4 + r];

    __syncthreads();   // pk ready

    // ---- P3: layer2 MFMA.  Wave owns ct = wv*4..wv*4+3, pt = 0..1.
    f32x4 acc[2][4];
#pragma unroll
    for (int a = 0; a < 2; ++a)
#pragma unroll
      for (int c = 0; c < 4; ++c)
        acc[a][c] = (f32x4){0.f, 0.f, 0.f, 0.f};

    const uint4* w2f4 = (const uint4*)w2f;
#pragma unroll
    for (int ks = 0; ks < 17; ++ks) {
      union { uint4 q; bf16x8 v; } A[4], B[2];
#pragma unroll
      for (int ctl = 0; ctl < 4; ++ctl)
        A[ctl].q = w2f4[(ks * 16 + wv * 4 + ctl) * 64 + lane];
#pragma unroll
      for (int pt = 0; pt < 2; ++pt) {
        const unsigned short* src = &pk[(pt * 16 + l15) * 548 + ks * 32 + l4 * 8];
        uint2 lo = *(const uint2*)src;
        uint2 hi = *(const uint2*)(src + 4);
        B[pt].q = make_uint4(lo.x, lo.y, hi.x, hi.y);
      }
#pragma unroll
      for (int pt = 0; pt < 2; ++pt)
#pragma unroll
        for (int ctl = 0; ctl < 4; ++ctl)
          acc[pt][ctl] = __builtin_amdgcn_mfma_f32_16x16x32_bf16(
              A[ctl].v, B[pt].v, acc[pt][ctl], 0, 0, 0);
    }

    // ---- epilogue: BN fold + relu, coalesced stores
#pragma unroll
    for (int pt = 0; pt < 2; ++pt) {
      int hw = hw0 + pt * 16 + l15;
#pragma unroll
      for (int ctl = 0; ctl < 4; ++ctl) {
        int ch = (wv * 4 + ctl) * 16 + l4 * 4;
#pragma unroll
        for (int r = 0; r < 4; ++r) {
          float v = fmaxf(acc[pt][ctl][r] + bet[ctl][r], 0.f);
          out[(((size_t)b * 256 + (ch + r)) << 12) + hw] = v;
        }
      }
    }
  }
}

// ---------------------------------------------------------------------------
extern "C" void kernel_launch(void* const* d_in, const int* in_sizes, int n_in,
                              void* d_out, int out_size, void* d_ws, size_t ws_size,
                              hipStream_t stream)
{
  const float* x   = (const float*)d_in[0];
  const float* w1  = (const float*)d_in[1];
  const float* b1  = (const float*)d_in[2];
  const float* g1  = (const float*)d_in[3];
  const float* be1 = (const float*)d_in[4];
  const float* m1  = (const float*)d_in[5];
  const float* v1  = (const float*)d_in[6];
  const float* w2  = (const float*)d_in[7];
  const float* b2  = (const float*)d_in[8];
  const float* g2  = (const float*)d_in[9];
  const float* be2 = (const float*)d_in[10];
  const float* m2  = (const float*)d_in[11];
  const float* v2  = (const float*)d_in[12];

  char* ws = (char*)d_ws;
  float*          beta1 = (float*)(ws);                  // 128 B
  float*          beta2 = (float*)(ws + 128);            // 1024 B
  unsigned short* w1b   = (unsigned short*)(ws + 1152);  // 16384 B
  unsigned short* w2f   = (unsigned short*)(ws + 17536); // 278528 B
  float* out = (float*)d_out;

  k_prep<<<dim3(544), dim3(256), 0, stream>>>(
      w1, b1, g1, be1, m1, v1, w2, b2, g2, be2, m2, v2, beta1, beta2, w1b, w2f);
  k_fused<<<dim3(1024), dim3(256), 0, stream>>>(x, w1b, beta1, w2f, beta2, out);
}

// Round 11
// 50.713 us; speedup vs baseline: 3.4187x; 3.4187x over previous
//
#include <hip/hip_runtime.h>

#define EPS 1e-5f

typedef float f32x4 __attribute__((ext_vector_type(4)));
typedef short bf16x8 __attribute__((ext_vector_type(8)));

__device__ __forceinline__ unsigned short f2bf(float f) {
  unsigned int u = __builtin_bit_cast(unsigned int, f);
  u = (u + 0x7FFFu + ((u >> 16) & 1u)) >> 16;
  return (unsigned short)u;
}

// HW packed f32->bf16 (RNE, bit-identical to f2bf; verified r10 absmax 0.0625)
__device__ __forceinline__ unsigned int cvt2(float a, float b) {
  unsigned int r;
  asm("v_cvt_pk_bf16_f32 %0, %1, %2" : "=v"(r) : "v"(a), "v"(b));
  return r;
}

// ---------------------------------------------------------------------------
// Prep (verified, unchanged): fold BN into weights; MFMA A-fragment layout
// (bf16), REFERENCE k-order.  idx = ((ks*CT + ct)*64 + lane)*8 + j
//   <-> A[ch = ct*16 + (lane&15)][k = ks*32 + (lane>>4)*8 + j]
// ---------------------------------------------------------------------------
__global__ __launch_bounds__(256) void k_prep(
    const float* __restrict__ w1, const float* __restrict__ b1,
    const float* __restrict__ g1, const float* __restrict__ be1,
    const float* __restrict__ m1, const float* __restrict__ v1,
    const float* __restrict__ w2, const float* __restrict__ b2,
    const float* __restrict__ g2, const float* __restrict__ be2,
    const float* __restrict__ m2, const float* __restrict__ v2,
    float* __restrict__ beta1, float* __restrict__ beta2,
    unsigned short* __restrict__ w1b, unsigned short* __restrict__ w2f)
{
  int t = blockIdx.x * 256 + threadIdx.x;
  if (t < 139264) {   // w2 fragments: 17 ks * 16 ct * 64 lanes * 8
    int j = t & 7, l = (t >> 3) & 63, g = t >> 9;
    int ct = g & 15, ks = g >> 4;
    int k = ks * 32 + (l >> 4) * 8 + j;
    int ch = ct * 16 + (l & 15);
    float val = 0.f;
    if (k < 528) {
      float s2 = g2[ch] * rsqrtf(v2[ch] + EPS);
      val = w2[ch * 528 + k] * s2;
    }
    w2f[t] = f2bf(val);
  }
  if (t < 8192) {     // w1 fragments: 8 ks * 2 ct * 64 lanes * 8
    int j = t & 7, l = (t >> 3) & 63, g = t >> 9;
    int ct = g & 1, ks = g >> 1;
    int c = ks * 32 + (l >> 4) * 8 + j;
    int m = ct * 16 + (l & 15);
    float s1 = g1[m] * rsqrtf(v1[m] + EPS);
    w1b[t] = f2bf(w1[m * 256 + c] * s1);
  }
  if (t < 32) {
    float s1 = g1[t] * rsqrtf(v1[t] + EPS);
    beta1[t] = (b1[t] - m1[t]) * s1 + be1[t];
  }
  if (t < 256) {
    float s2 = g2[t] * rsqrtf(v2[t] + EPS);
    beta2[t] = (b2[t] - m2[t]) * s2 + be2[t];
  }
}

// Write diag I (reference order, len 32-I at base(I)) from register y-row.
template<int I>
__device__ __forceinline__ void do_diag(const float* __restrict__ y,
                                        unsigned short* __restrict__ pr)
{
  constexpr int L = 32 - I;
  constexpr int base = 32 * I - (I * (I - 1)) / 2;
  float p[L];
#pragma unroll
  for (int j = 0; j < L; ++j) p[j] = y[I + j] * y[j];
  constexpr int s = (base & 1) ? 1 : 0;
  if constexpr (s != 0) pr[base] = f2bf(p[0]);
#pragma unroll
  for (int j = s; j + 1 < L; j += 2)
    *(unsigned int*)&pr[base + j] = cvt2(p[j], p[j + 1]);
  if constexpr (((L - s) & 1) != 0) pr[base + L - 1] = f2bf(p[L - 1]);
}

// Balanced set (verified r4/r7): diags {S, 31-S, S+8, 23-S} = 66 products.
template<int S>
__device__ __forceinline__ void do_set(const float* __restrict__ y,
                                       unsigned short* __restrict__ pr)
{
  do_diag<S>(y, pr);
  do_diag<31 - S>(y, pr);
  do_diag<S + 8>(y, pr);
  do_diag<23 - S>(y, pr);
}

// One 32-px half of P2: EXACTLY the verified r4 partition (8 sets x 4 diags,
// 8 threads/px), operating on a 32-px slice of yf/pk.
__device__ __forceinline__ void p2_half(const float* __restrict__ yfh,
                                        unsigned short* __restrict__ pkh,
                                        int tid)
{
  int px2 = tid & 31, set = tid >> 5;
  const float* yr = &yfh[px2 * 34];
  unsigned short* pr = &pkh[px2 * 548];
  float y[32];
#pragma unroll
  for (int k = 0; k < 16; ++k) {
    float2 v = *(const float2*)&yr[2 * k];
    y[2 * k] = v.x; y[2 * k + 1] = v.y;
  }
  switch (set) {
    case 0: do_set<0>(y, pr); break;
    case 1: do_set<1>(y, pr); break;
    case 2: do_set<2>(y, pr); break;
    case 3: do_set<3>(y, pr); break;
    case 4: do_set<4>(y, pr); break;
    case 5: do_set<5>(y, pr); break;
    case 6: do_set<6>(y, pr); break;
    default: do_set<7>(y, pr); break;
  }
  if (set < 4) {   // zero K-pad slots 528..543
    *(unsigned int*)&pr[528 + set * 4] = 0u;
    *(unsigned int*)&pr[530 + set * 4] = 0u;
  }
}

// ---------------------------------------------------------------------------
// Fused, 64-pixel tiles (1024 blocks, 2 blocks/CU): halves per-CU w2f
// A-fragment traffic vs 32-px tiles (the dominant per-CU shared term).
// Composition of bit-verified pieces only:
//  P0: r2's x->bf16 [px][276] staging (64 px)                 (barrier)
//  P1: r2's layer1 MFMA (wave owns 16 px, 2 ct) -> yf         (barrier)
//  P2: r4's verified 8-set partition, run twice (px halves)    (barrier)
//  P3: r2's 17 ks x 4 ct x 4 pt MFMA + BN/relu + stores
// LDS: pk 70144B (xt 35328B aliases) + yf 8704B = 78848B.
// ---------------------------------------------------------------------------
__global__ __launch_bounds__(256) void k_fused(
    const float* __restrict__ x, const unsigned short* __restrict__ w1b,
    const float* __restrict__ beta1, const unsigned short* __restrict__ w2f,
    const float* __restrict__ beta2, float* __restrict__ out)
{
  __shared__ __align__(16) unsigned short pk[64 * 548];
  __shared__ __align__(8) float yf[64 * 34];
  int tid = threadIdx.x;
  int wv = tid >> 6, lane = tid & 63;
  int l15 = lane & 15, l4 = lane >> 4;
  int g = blockIdx.x;
  int orig = ((g & 7) << 7) + (g >> 3);   // bijective XCD swizzle (1024%8==0)
  int pb = orig * 64;
  int b = pb >> 12, hw0 = pb & 4095;
  const float* xb = x + ((size_t)b << 20) + hw0;

  // ---- P0 (r2): stage x -> bf16 transposed tile (row = px, stride 276)
  unsigned short* xt = pk;
  {
    int q = tid & 15;        // px quad (4*q .. 4*q+3), 16 quads = 64 px
    int c40 = tid >> 4;      // channel quad within pass
#pragma unroll
    for (int pass = 0; pass < 4; ++pass) {
      int c4 = c40 + pass * 16;   // ch = 4*c4 + i
      float4 v[4];
#pragma unroll
      for (int i = 0; i < 4; ++i)
        v[i] = *(const float4*)&xb[(size_t)(4 * c4 + i) * 4096 + 4 * q];
#pragma unroll
      for (int s = 0; s < 4; ++s) {
        const float* e0 = (const float*)&v[0];
        const float* e1 = (const float*)&v[1];
        const float* e2 = (const float*)&v[2];
        const float* e3 = (const float*)&v[3];
        *(uint2*)&xt[(4 * q + s) * 276 + 4 * c4] =
            make_uint2(cvt2(e0[s], e1[s]), cvt2(e2[s], e3[s]));
      }
    }
  }
  __syncthreads();

  // ---- P1 (r2): layer1 MFMA; wave owns px = wv*16+l15, both ct
  {
    int px = wv * 16 + l15;
    f32x4 acc1[2];
    acc1[0] = (f32x4){0.f, 0.f, 0.f, 0.f};
    acc1[1] = (f32x4){0.f, 0.f, 0.f, 0.f};
    const uint4* w1b4 = (const uint4*)w1b;
#pragma unroll
    for (int ks = 0; ks < 8; ++ks) {
      union { uint4 q; bf16x8 v; } A0, A1, B;
      A0.q = w1b4[(ks * 2 + 0) * 64 + lane];
      A1.q = w1b4[(ks * 2 + 1) * 64 + lane];
      const unsigned short* s = &xt[px * 276 + ks * 32 + l4 * 8];
      uint2 lo = *(const uint2*)s;
      uint2 hi = *(const uint2*)(s + 4);
      B.q = make_uint4(lo.x, lo.y, hi.x, hi.y);
      acc1[0] = __builtin_amdgcn_mfma_f32_16x16x32_bf16(A0.v, B.v, acc1[0], 0, 0, 0);
      acc1[1] = __builtin_amdgcn_mfma_f32_16x16x32_bf16(A1.v, B.v, acc1[1], 0, 0, 0);
    }
#pragma unroll
    for (int ct = 0; ct < 2; ++ct) {
      int m0 = ct * 16 + l4 * 4;
#pragma unroll
      for (int r = 0; r < 4; ++r)
        yf[px * 34 + m0 + r] = fmaxf(acc1[ct][r] + beta1[m0 + r], 0.f);
    }
  }
  __syncthreads();   // xt consumed AND yf ready; pk region free

  // ---- P2: r4's verified partition, twice (one per 32-px half)
  p2_half(yf, pk, tid);
  p2_half(yf + 32 * 34, pk + 32 * 548, tid);

  // beta2 loads before the barrier; latency hides under P3
  float bet[4][4];
#pragma unroll
  for (int ctl = 0; ctl < 4; ++ctl)
#pragma unroll
    for (int r = 0; r < 4; ++r)
      bet[ctl][r] = beta2[(wv * 4 + ctl) * 16 + l4 * 4 + r];

  __syncthreads();   // pk ready

  // ---- P3 (r2): layer2 MFMA.  Wave owns ct = wv*4..wv*4+3, pt = 0..3.
  f32x4 acc[4][4];
#pragma unroll
  for (int a = 0; a < 4; ++a)
#pragma unroll
    for (int c = 0; c < 4; ++c)
      acc[a][c] = (f32x4){0.f, 0.f, 0.f, 0.f};

  const uint4* w2f4 = (const uint4*)w2f;
  for (int ks = 0; ks < 17; ++ks) {
    union { uint4 q; bf16x8 v; } A[4], B[4];
#pragma unroll
    for (int ctl = 0; ctl < 4; ++ctl)
      A[ctl].q = w2f4[(ks * 16 + wv * 4 + ctl) * 64 + lane];
#pragma unroll
    for (int pt = 0; pt < 4; ++pt) {
      const unsigned short* src = &pk[(pt * 16 + l15) * 548 + ks * 32 + l4 * 8];
      uint2 lo = *(const uint2*)src;
      uint2 hi = *(const uint2*)(src + 4);
      B[pt].q = make_uint4(lo.x, lo.y, hi.x, hi.y);
    }
#pragma unroll
    for (int pt = 0; pt < 4; ++pt)
#pragma unroll
      for (int ctl = 0; ctl < 4; ++ctl)
        acc[pt][ctl] = __builtin_amdgcn_mfma_f32_16x16x32_bf16(
            A[ctl].v, B[pt].v, acc[pt][ctl], 0, 0, 0);
  }

  // ---- epilogue (r2): BN fold + relu, coalesced stores
#pragma unroll
  for (int pt = 0; pt < 4; ++pt) {
    int hw = hw0 + pt * 16 + l15;
#pragma unroll
    for (int ctl = 0; ctl < 4; ++ctl) {
      int ch = (wv * 4 + ctl) * 16 + l4 * 4;
#pragma unroll
      for (int r = 0; r < 4; ++r) {
        float v = fmaxf(acc[pt][ctl][r] + bet[ctl][r], 0.f);
        out[(((size_t)b * 256 + (ch + r)) << 12) + hw] = v;
      }
    }
  }
}

// ---------------------------------------------------------------------------
extern "C" void kernel_launch(void* const* d_in, const int* in_sizes, int n_in,
                              void* d_out, int out_size, void* d_ws, size_t ws_size,
                              hipStream_t stream)
{
  const float* x   = (const float*)d_in[0];
  const float* w1  = (const float*)d_in[1];
  const float* b1  = (const float*)d_in[2];
  const float* g1  = (const float*)d_in[3];
  const float* be1 = (const float*)d_in[4];
  const float* m1  = (const float*)d_in[5];
  const float* v1  = (const float*)d_in[6];
  const float* w2  = (const float*)d_in[7];
  const float* b2  = (const float*)d_in[8];
  const float* g2  = (const float*)d_in[9];
  const float* be2 = (const float*)d_in[10];
  const float* m2  = (const float*)d_in[11];
  const float* v2  = (const float*)d_in[12];

  char* ws = (char*)d_ws;
  float*          beta1 = (float*)(ws);                  // 128 B
  float*          beta2 = (float*)(ws + 128);            // 1024 B
  unsigned short* w1b   = (unsigned short*)(ws + 1152);  // 16384 B
  unsigned short* w2f   = (unsigned short*)(ws + 17536); // 278528 B
  float* out = (float*)d_out;

  k_prep<<<dim3(544), dim3(256), 0, stream>>>(
      w1, b1, g1, be1, m1, v1, w2, b2, g2, be2, m2, v2, beta1, beta2, w1b, w2f);
  k_fused<<<dim3(1024), dim3(256), 0, stream>>>(x, w1b, beta1, w2f, beta2, out);
}